// Round 12
// baseline (180.811 us; speedup 1.0000x reference)
//
#include <hip/hip_runtime.h>
#include <math.h>

// ---------- types ----------
using f32x4  = __attribute__((ext_vector_type(4))) float;
using bf16x8 = __attribute__((ext_vector_type(8))) short;   // 8 bf16 in 4 VGPRs
using us8    = __attribute__((ext_vector_type(8))) unsigned short;
using us4    = __attribute__((ext_vector_type(4))) unsigned short;

static __device__ __forceinline__ unsigned short f32_bf16(float f) {
    unsigned int u = __float_as_uint(f);
    u += 0x7fffu + ((u >> 16) & 1u);       // round-to-nearest-even
    return (unsigned short)(u >> 16);
}

static __device__ __forceinline__ float fast_exp2(float x) {
    return __builtin_amdgcn_exp2f(x);      // v_exp_f32 (2^x)
}

// pack 2 f32 -> 2 bf16 in one u32 (RNE), single instruction
static __device__ __forceinline__ unsigned int bf16pk(float lo, float hi) {
    unsigned int r;
    asm("v_cvt_pk_bf16_f32 %0, %1, %2" : "=v"(r) : "v"(lo), "v"(hi));
    return r;
}

// global -> LDS direct copy, 16B per lane. LDS dest is wave-uniform base +
// lane*16 (linear); swizzling is done on the per-lane GLOBAL source address.
#define GLOADLDS16(src, dst)                                                          \
    __builtin_amdgcn_global_load_lds(                                                 \
        (const __attribute__((address_space(1))) void*)(src),                         \
        (__attribute__((address_space(3))) void*)(dst), 16, 0, 0)

// ---------- fused prep: x->bf16 | W->W^T bf16 | relation scores ----------
__global__ __launch_bounds__(256) void prep_kernel(
    const float* __restrict__ x, const float* __restrict__ Wq,
    const float* __restrict__ Wk, const float* __restrict__ Wv,
    const float* __restrict__ Wo, const float* __restrict__ Wrel,
    const float* __restrict__ brel, unsigned short* __restrict__ xb,
    unsigned short* __restrict__ wqkvT, unsigned short* __restrict__ woT,
    float* __restrict__ out) {
    const int bid = blockIdx.x;
    if (bid < 8192) {                       // conv_x: 2M float4s
        const int i = bid * 256 + threadIdx.x;
        const float4 v = ((const float4*)x)[i];
        us4 o;
        o.x = f32_bf16(v.x); o.y = f32_bf16(v.y);
        o.z = f32_bf16(v.z); o.w = f32_bf16(v.w);
        ((us4*)xb)[i] = o;
        return;
    }
    if (bid < 12288) {                      // conv_wT: transpose 4 weight mats
        __shared__ float t[32][33];
        const int z = bid - 8192;
        const int zz = z >> 10;             // 0..3
        const float* W = (zz == 0) ? Wq : (zz == 1) ? Wk : (zz == 2) ? Wv : Wo;
        unsigned short* dst = (zz < 3) ? (wqkvT + (size_t)zz * 1024 * 1024) : woT;
        const int bx = (z & 31) * 32, by = ((z >> 5) & 31) * 32;
        const int tx = threadIdx.x & 31, ty = threadIdx.x >> 5;
#pragma unroll
        for (int i = ty; i < 32; i += 8)
            t[i][tx] = W[(size_t)(by + i) * 1024 + bx + tx];
        __syncthreads();
#pragma unroll
        for (int i = ty; i < 32; i += 8)
            dst[(size_t)(bx + i) * 1024 + by + tx] = f32_bf16(t[tx][i]);
        return;
    }
    // relation scores: softmax rows sum to 1 -> head_patterns == 1/L exactly
    const int t = threadIdx.x;
    if (t < 64) {
        const int r = t & 7;
        float s = 0.f;
#pragma unroll
        for (int hh = 0; hh < 16; ++hh) s += Wrel[hh * 8 + r];
        out[8 * 1024 * 1024 + t] = s * (1.0f / 1024.0f) + brel[r];
    }
}

// ---------- GEMM: C[M,N] = A[M,K] * Bt[N,K]^T, K=1024 ----------
// 256x128 tile, 256 thr (4 waves 2x2, per-wave 128x64, acc[8][4]).
// BK=32, 3-BUFFER RING (3 x 24 KB = 72 KB -> 2 blocks/CU) with counted vmcnt:
// step s reads buf[s%3], issues the 6 loads of step s+2 into buf[(s+2)%3],
// waits vmcnt(6) (never 0) -> every load has >= 1 full step of compute cover.
// Bank swizzle for 64B rows: chunk' = chunk ^ ((row>>1)&3) (uniform spread).
// Operands SWAPPED in mfma (C^T): lane holds 4 consecutive N.
template<int MODE>
__global__ __launch_bounds__(256, 2) void gemm_bt_kernel(
    const unsigned short* __restrict__ A, const unsigned short* __restrict__ Bt,
    const float* __restrict__ bias_q, const float* __restrict__ bias_k,
    const float* __restrict__ bias_v,
    unsigned short* __restrict__ qkv, float* __restrict__ cout) {
    constexpr int K = 1024;
    constexpr int AE = 256 * 32;             // elems per A buffer (16 KB)
    constexpr int BE = 128 * 32;             // elems per B buffer (8 KB)
    __shared__ unsigned short As[3 * AE];    // 48 KB
    __shared__ unsigned short Bs[3 * BE];    // 24 KB
    const int tid = threadIdx.x;
    const int wid = tid >> 6, lane = tid & 63;
    const int bm = blockIdx.x * 256, bn = blockIdx.y * 128;
    const int wr = wid >> 1, wc = wid & 1;       // 2x2 waves; wave tile 128x64
    const int l15 = lane & 15, lg = lane >> 4;
    // staging: instance covers 16 rows; lane -> row l>>2, src chunk swizzled
    const int srow = lane >> 2;                  // 0..15
    const int csrc = (lane & 3) ^ ((lane >> 3) & 3);

    f32x4 acc[8][4] = {};

    // per-wave staging bases (element offsets into a buffer)
    //   A instances: ai = wid*4+j (16 total), rows ai*16..+15
    //   B instances: bi = wid*2+j (8 total)
#define STAGE(T, BUF)                                                                 \
    do {                                                                              \
        _Pragma("unroll")                                                             \
        for (int j = 0; j < 4; ++j) {                                                 \
            const int ai = wid * 4 + j;                                               \
            GLOADLDS16(A + (size_t)(bm + ai * 16 + srow) * K + (T) * 32 + csrc * 8,   \
                       &As[(BUF) * AE + ai * 512]);                                   \
        }                                                                             \
        _Pragma("unroll")                                                             \
        for (int j = 0; j < 2; ++j) {                                                 \
            const int bi = wid * 2 + j;                                               \
            GLOADLDS16(Bt + (size_t)(bn + bi * 16 + srow) * K + (T) * 32 + csrc * 8,  \
                       &Bs[(BUF) * BE + bi * 512]);                                   \
        }                                                                             \
    } while (0)

    // prologue: stage steps 0,1 into bufs 0,1
    STAGE(0, 0);
    STAGE(1, 1);
    asm volatile("s_waitcnt vmcnt(6)" ::: "memory");   // step 0 landed
    __builtin_amdgcn_s_barrier();

    // frag-read chunk (same swizzle; row base multiples of 16 drop out)
    const int cfr = lg ^ ((l15 >> 1) & 3);
    const int arow0 = (wr * 128 + l15) * 32 + cfr * 8;   // + m*16*32
    const int brow0 = (wc * 64 + l15) * 32 + cfr * 8;    // + n*16*32

    int rbuf = 0, wbuf = 2;
    for (int s = 0; s < 32; ++s) {
        if (s < 30) STAGE(s + 2, wbuf);          // issue-early, lands in ~2 steps

        const unsigned short* Ab = &As[rbuf * AE];
        const unsigned short* Bb = &Bs[rbuf * BE];
        bf16x8 bfr[4];
#pragma unroll
        for (int n = 0; n < 4; ++n)
            bfr[n] = *(const bf16x8*)&Bb[brow0 + n * 512];
        __builtin_amdgcn_s_setprio(1);
#pragma unroll
        for (int m = 0; m < 8; ++m) {
            const bf16x8 af = *(const bf16x8*)&Ab[arow0 + m * 512];
#pragma unroll
            for (int n = 0; n < 4; ++n)
                acc[m][n] = __builtin_amdgcn_mfma_f32_16x16x32_bf16(
                    bfr[n], af, acc[m][n], 0, 0, 0);
        }
        __builtin_amdgcn_s_setprio(0);

        if (s < 30)      asm volatile("s_waitcnt vmcnt(6)" ::: "memory");
        else if (s == 30) asm volatile("s_waitcnt vmcnt(0)" ::: "memory");
        __builtin_amdgcn_s_barrier();

        rbuf = (rbuf == 2) ? 0 : rbuf + 1;
        wbuf = (wbuf == 2) ? 0 : wbuf + 1;
    }
#undef STAGE

    // epilogue (C^T layout): gm = ... + l15 (fixed per lane), gn = ... + lg*4 + r
    if constexpr (MODE == 0) {
        const int which = bn >> 10;               // uniform per block (128 | 1024)
        const int hnb = (bn & 1023) + wc * 64;
        const float* bias = (which == 0) ? bias_q : (which == 1) ? bias_k : bias_v;
        if (which == 2) {
            // V transposed: vT[b][h][d][l]; lane's r-values are consecutive d
#pragma unroll
            for (int m = 0; m < 8; ++m) {
                const int gm = bm + wr * 128 + m * 16 + l15;
                const int b_ = gm >> 10, li2 = gm & 1023;
#pragma unroll
                for (int n = 0; n < 4; ++n) {
                    const int hn0 = hnb + n * 16 + lg * 4;
                    const float4 bb = *(const float4*)&bias[hn0];
                    const float vv[4] = {acc[m][n][0] + bb.x, acc[m][n][1] + bb.y,
                                         acc[m][n][2] + bb.z, acc[m][n][3] + bb.w};
#pragma unroll
                    for (int r = 0; r < 4; ++r) {
                        const int hn = hn0 + r;
                        qkv[16777216 +
                            ((size_t)(b_ * 16 + (hn >> 6)) * 64 + (hn & 63)) * 1024 +
                            li2] = f32_bf16(vv[r]);
                    }
                }
            }
        } else {
            const float qs = (which == 0) ? 0.125f * 1.44269504088896f : 1.0f;
#pragma unroll
            for (int m = 0; m < 8; ++m) {
                const int gm = bm + wr * 128 + m * 16 + l15;
                const size_t rowbase =
                    (((size_t)which * 128 + (gm >> 10) * 16) * 1024 + (gm & 1023)) * 64;
#pragma unroll
                for (int n = 0; n < 4; ++n) {
                    const int hn0 = hnb + n * 16 + lg * 4;   // 4-aligned
                    const float4 bb = *(const float4*)&bias[hn0];
                    const unsigned int w01 = bf16pk((acc[m][n][0] + bb.x) * qs,
                                                    (acc[m][n][1] + bb.y) * qs);
                    const unsigned int w23 = bf16pk((acc[m][n][2] + bb.z) * qs,
                                                    (acc[m][n][3] + bb.w) * qs);
                    uint2 t2; t2.x = w01; t2.y = w23;
                    *(uint2*)&qkv[rowbase + (size_t)(hn0 >> 6) * 65536 + (hn0 & 63)] = t2;
                }
            }
        }
    } else {
#pragma unroll
        for (int m = 0; m < 8; ++m) {
            const int gm = bm + wr * 128 + m * 16 + l15;
#pragma unroll
            for (int n = 0; n < 4; ++n) {
                const int gn0 = bn + wc * 64 + n * 16 + lg * 4;
                const float4 bb = *(const float4*)&bias_q[gn0];
                float4 o;
                o.x = acc[m][n][0] + bb.x; o.y = acc[m][n][1] + bb.y;
                o.z = acc[m][n][2] + bb.z; o.w = acc[m][n][3] + bb.w;
                *(float4*)&cout[(size_t)gm * 1024 + gn0] = o;
            }
        }
    }
}

// ---------- flash attention v4: 32 q-rows per wave (two 16-row strips) ----------
// grid: (B*H, L/128); block 256 = 4 waves. Each K/V fragment is read from LDS
// ONCE and feeds MFMAs for BOTH strips.
__global__ __launch_bounds__(256, 2) void attn_kernel(
    const unsigned short* __restrict__ qkv, unsigned short* __restrict__ ctx) {
    __shared__ unsigned short Ks[2][4096];      // [key][d] XOR-swizzled, dbuf 16KB
    __shared__ unsigned short VTs[2][4096];     // [d][key] XOR-swizzled, dbuf 16KB
    __shared__ unsigned short Ps[4][2][1024];   // per-wave-strip P, 16KB
    const int bh = blockIdx.x, qt = blockIdx.y;
    const int b = bh >> 4, h = bh & 15;
    const unsigned short* Qp  = qkv + (size_t)bh * 65536;
    const unsigned short* Kp  = qkv + 8388608  + (size_t)bh * 65536;
    const unsigned short* VTp = qkv + 16777216 + (size_t)bh * 65536;  // [64][1024]
    const int tid = threadIdx.x, wid = tid >> 6, lane = tid & 63;
    const int l15 = lane & 15, lg = lane >> 4;
    const int q0 = qt * 128 + wid * 32;         // wave owns rows q0..q0+31
    const int srow = lane >> 3;
    const int schunk = (lane & 7) ^ srow;

    // Q fragments for both strips (pre-scaled by log2e/8)
    bf16x8 qf[2][2];
#pragma unroll
    for (int s = 0; s < 2; ++s)
#pragma unroll
        for (int ks = 0; ks < 2; ++ks)
            qf[s][ks] = *(const bf16x8*)(Qp + (size_t)(q0 + s * 16 + l15) * 64 +
                                         ks * 32 + lg * 8);

    f32x4 oacc[2][4] = {};
    float lrow[2] = {0.f, 0.f};

    int koff[4][2], poff_r[2], poff_w[4];
#pragma unroll
    for (int nf = 0; nf < 4; ++nf)
#pragma unroll
        for (int ks = 0; ks < 2; ++ks) {
            const int row = nf * 16 + l15;
            koff[nf][ks] = row * 64 + (((ks * 4 + lg) ^ (row & 7)) * 8);
        }
#pragma unroll
    for (int ks = 0; ks < 2; ++ks)
        poff_r[ks] = l15 * 64 + (((ks * 4 + lg) ^ (l15 & 7)) * 8);
#pragma unroll
    for (int nf = 0; nf < 4; ++nf) {
        const int cchunk = nf * 2 + (lg >> 1);
        poff_w[nf] = l15 * 64 + ((cchunk ^ (l15 & 7)) * 8) + (lg & 1) * 4;
    }

#define ATTN_STAGE(KT, BB)                                                            \
    do {                                                                              \
        _Pragma("unroll")                                                             \
        for (int i = 0; i < 2; ++i) {                                                 \
            const int li = wid * 2 + i;                                               \
            GLOADLDS16(Kp + (size_t)((KT) * 64 + li * 8 + srow) * 64 + schunk * 8,    \
                       &Ks[BB][li * 512]);                                            \
            GLOADLDS16(VTp + (size_t)(li * 8 + srow) * 1024 + (KT) * 64 + schunk * 8, \
                       &VTs[BB][li * 512]);                                           \
        }                                                                             \
    } while (0)

    ATTN_STAGE(0, 0);
    for (int kt = 0; kt < 16; ++kt) {
        const int cur = kt & 1;
        if (kt < 15) {
            ATTN_STAGE(kt + 1, cur ^ 1);
            asm volatile("s_waitcnt vmcnt(4)" ::: "memory");  // tile kt landed
        } else {
            asm volatile("s_waitcnt vmcnt(0)" ::: "memory");
        }
        __builtin_amdgcn_s_barrier();

        const unsigned short* Kb = &Ks[cur][0];
        const unsigned short* Vb = &VTs[cur][0];

        // S^T = K Q^T for both strips; each kf read once, used twice
        f32x4 sacc[2][4] = {};
        __builtin_amdgcn_s_setprio(1);
#pragma unroll
        for (int ks = 0; ks < 2; ++ks)
#pragma unroll
            for (int nf = 0; nf < 4; ++nf) {
                const bf16x8 kf = *(const bf16x8*)&Kb[koff[nf][ks]];
                sacc[0][nf] = __builtin_amdgcn_mfma_f32_16x16x32_bf16(
                    kf, qf[0][ks], sacc[0][nf], 0, 0, 0);
                sacc[1][nf] = __builtin_amdgcn_mfma_f32_16x16x32_bf16(
                    kf, qf[1][ks], sacc[1][nf], 0, 0, 0);
            }
        __builtin_amdgcn_s_setprio(0);

        // no-max softmax per strip: p = 2^s, partial sums, cvt_pk pack
#pragma unroll
        for (int s = 0; s < 2; ++s) {
            unsigned short* Pw = &Ps[wid][s][0];
            float rsa = 0.f, rsb = 0.f;
#pragma unroll
            for (int nf = 0; nf < 4; ++nf) {
                const float p0 = fast_exp2(sacc[s][nf][0]);
                const float p1 = fast_exp2(sacc[s][nf][1]);
                const float p2 = fast_exp2(sacc[s][nf][2]);
                const float p3 = fast_exp2(sacc[s][nf][3]);
                rsa += p0 + p1; rsb += p2 + p3;
                uint2 t; t.x = bf16pk(p0, p1); t.y = bf16pk(p2, p3);
                *(uint2*)&Pw[poff_w[nf]] = t;
            }
            lrow[s] += rsa + rsb;
        }

        // O^T += V^T P for both strips; each vf read once, used twice
        __builtin_amdgcn_s_setprio(1);
#pragma unroll
        for (int ks = 0; ks < 2; ++ks) {
            const bf16x8 pf0 = *(const bf16x8*)&Ps[wid][0][poff_r[ks]];
            const bf16x8 pf1 = *(const bf16x8*)&Ps[wid][1][poff_r[ks]];
#pragma unroll
            for (int nf = 0; nf < 4; ++nf) {
                const bf16x8 vf = *(const bf16x8*)&Vb[koff[nf][ks]];
                oacc[0][nf] = __builtin_amdgcn_mfma_f32_16x16x32_bf16(
                    vf, pf0, oacc[0][nf], 0, 0, 0);
                oacc[1][nf] = __builtin_amdgcn_mfma_f32_16x16x32_bf16(
                    vf, pf1, oacc[1][nf], 0, 0, 0);
            }
        }
        __builtin_amdgcn_s_setprio(0);

        __builtin_amdgcn_s_barrier();
    }
#undef ATTN_STAGE

    // cross-lane l reduction + normalize + write, per strip
#pragma unroll
    for (int s = 0; s < 2; ++s) {
        float l = lrow[s];
        l += __shfl_xor(l, 16);
        l += __shfl_xor(l, 32);
        const float rl = 1.0f / l;
#pragma unroll
        for (int nf = 0; nf < 4; ++nf) {
            uint2 t;
            t.x = bf16pk(oacc[s][nf][0] * rl, oacc[s][nf][1] * rl);
            t.y = bf16pk(oacc[s][nf][2] * rl, oacc[s][nf][3] * rl);
            *(uint2*)&ctx[((size_t)(b * 1024 + q0 + s * 16 + l15)) * 1024 + h * 64 +
                          nf * 16 + lg * 4] = t;
        }
    }
}

// ---------- launch ----------
extern "C" void kernel_launch(void* const* d_in, const int* in_sizes, int n_in,
                              void* d_out, int out_size, void* d_ws, size_t ws_size,
                              hipStream_t stream) {
    (void)in_sizes; (void)n_in; (void)out_size; (void)ws_size;
    const float* x    = (const float*)d_in[0];
    const float* Wq   = (const float*)d_in[1];
    const float* bq   = (const float*)d_in[2];
    const float* Wk   = (const float*)d_in[3];
    const float* bk   = (const float*)d_in[4];
    const float* Wv   = (const float*)d_in[5];
    const float* bv   = (const float*)d_in[6];
    const float* Wo   = (const float*)d_in[7];
    const float* bo   = (const float*)d_in[8];
    const float* Wrel = (const float*)d_in[9];
    const float* brel = (const float*)d_in[10];
    float* out = (float*)d_out;

    char* ws = (char*)d_ws;
    unsigned short* xb    = (unsigned short*)ws;                           // 16 MB
    unsigned short* wqkvT = (unsigned short*)(ws + 16777216);              // 6 MB
    unsigned short* woT   = (unsigned short*)(ws + 16777216 + 6291456);    // 2 MB
    unsigned short* qkv   = (unsigned short*)(ws + 16777216 + 6291456 + 2097152); // 48 MB
    unsigned short* ctx   = xb;  // xb dead after QKV GEMM -> reuse for ctx

    prep_kernel<<<12289, 256, 0, stream>>>(x, Wq, Wk, Wv, Wo, Wrel, brel,
                                           xb, wqkvT, woT, out);
    gemm_bt_kernel<0><<<dim3(32, 24), 256, 0, stream>>>(
        xb, wqkvT, bq, bk, bv, qkv, nullptr);
    attn_kernel<<<dim3(128, 8), 256, 0, stream>>>(qkv, ctx);
    gemm_bt_kernel<1><<<dim3(32, 8), 256, 0, stream>>>(
        ctx, woT, bo, nullptr, nullptr, nullptr, out);
}

// Round 13
// 160.012 us; speedup vs baseline: 1.1300x; 1.1300x over previous
//
#include <hip/hip_runtime.h>
#include <math.h>

// ---------- types ----------
using f32x4  = __attribute__((ext_vector_type(4))) float;
using bf16x8 = __attribute__((ext_vector_type(8))) short;   // 8 bf16 in 4 VGPRs
using us8    = __attribute__((ext_vector_type(8))) unsigned short;
using us4    = __attribute__((ext_vector_type(4))) unsigned short;

static __device__ __forceinline__ unsigned short f32_bf16(float f) {
    unsigned int u = __float_as_uint(f);
    u += 0x7fffu + ((u >> 16) & 1u);       // round-to-nearest-even
    return (unsigned short)(u >> 16);
}

static __device__ __forceinline__ float fast_exp2(float x) {
    return __builtin_amdgcn_exp2f(x);      // v_exp_f32 (2^x)
}

// pack 2 f32 -> 2 bf16 in one u32 (RNE), single instruction
static __device__ __forceinline__ unsigned int bf16pk(float lo, float hi) {
    unsigned int r;
    asm("v_cvt_pk_bf16_f32 %0, %1, %2" : "=v"(r) : "v"(lo), "v"(hi));
    return r;
}

// global -> LDS direct copy, 16B per lane. LDS dest is wave-uniform base +
// lane*16 (linear); swizzling is done on the per-lane GLOBAL source address.
#define GLOADLDS16(src, dst)                                                          \
    __builtin_amdgcn_global_load_lds(                                                 \
        (const __attribute__((address_space(1))) void*)(src),                         \
        (__attribute__((address_space(3))) void*)(dst), 16, 0, 0)

// ---------- fused prep: x->bf16 | W->W^T bf16 | relation scores ----------
__global__ __launch_bounds__(256) void prep_kernel(
    const float* __restrict__ x, const float* __restrict__ Wq,
    const float* __restrict__ Wk, const float* __restrict__ Wv,
    const float* __restrict__ Wo, const float* __restrict__ Wrel,
    const float* __restrict__ brel, unsigned short* __restrict__ xb,
    unsigned short* __restrict__ wqkvT, unsigned short* __restrict__ woT,
    float* __restrict__ out) {
    const int bid = blockIdx.x;
    if (bid < 8192) {                       // conv_x: 2M float4s
        const int i = bid * 256 + threadIdx.x;
        const float4 v = ((const float4*)x)[i];
        us4 o;
        o.x = f32_bf16(v.x); o.y = f32_bf16(v.y);
        o.z = f32_bf16(v.z); o.w = f32_bf16(v.w);
        ((us4*)xb)[i] = o;
        return;
    }
    if (bid < 12288) {                      // conv_wT: transpose 4 weight mats
        __shared__ float t[32][33];
        const int z = bid - 8192;
        const int zz = z >> 10;             // 0..3
        const float* W = (zz == 0) ? Wq : (zz == 1) ? Wk : (zz == 2) ? Wv : Wo;
        unsigned short* dst = (zz < 3) ? (wqkvT + (size_t)zz * 1024 * 1024) : woT;
        const int bx = (z & 31) * 32, by = ((z >> 5) & 31) * 32;
        const int tx = threadIdx.x & 31, ty = threadIdx.x >> 5;
#pragma unroll
        for (int i = ty; i < 32; i += 8)
            t[i][tx] = W[(size_t)(by + i) * 1024 + bx + tx];
        __syncthreads();
#pragma unroll
        for (int i = ty; i < 32; i += 8)
            dst[(size_t)(bx + i) * 1024 + by + tx] = f32_bf16(t[tx][i]);
        return;
    }
    // relation scores: softmax rows sum to 1 -> head_patterns == 1/L exactly
    const int t = threadIdx.x;
    if (t < 64) {
        const int r = t & 7;
        float s = 0.f;
#pragma unroll
        for (int hh = 0; hh < 16; ++hh) s += Wrel[hh * 8 + r];
        out[8 * 1024 * 1024 + t] = s * (1.0f / 1024.0f) + brel[r];
    }
}

// ---------- GEMM (round-9 best, FROZEN): 256x128 tile, 256 thr, acc[8][4] ----------
// C[M,N] = A[M,K] * Bt[N,K]^T, K=1024. Per-wave 128x64 -> 6 B LDS read/MFMA.
// Single-buffer 48 KB LDS, 2 blocks/CU. Plain 2-sync loop: 5 schedule variants
// (R5/R6/R7/R11-ring/R12) all regressed vs this -- compiler+co-residency wins.
// Operands SWAPPED in mfma (C^T): lane holds 4 consecutive N.
template<int MODE>
__global__ __launch_bounds__(256, 2) void gemm_bt_kernel(
    const unsigned short* __restrict__ A, const unsigned short* __restrict__ Bt,
    const float* __restrict__ bias_q, const float* __restrict__ bias_k,
    const float* __restrict__ bias_v,
    unsigned short* __restrict__ qkv, float* __restrict__ cout) {
    constexpr int K = 1024;
    __shared__ unsigned short As[256 * 64];   // 32 KB
    __shared__ unsigned short Bs[128 * 64];   // 16 KB
    const int tid = threadIdx.x;
    const int wid = tid >> 6, lane = tid & 63;
    const int bm = blockIdx.x * 256, bn = blockIdx.y * 128;
    const int wr = wid >> 1, wc = wid & 1;       // 2x2 waves; wave tile 128x64
    const int l15 = lane & 15, lg = lane >> 4;
    const int srow = lane >> 3;                  // row-within-8 for staging
    const int schunk = (lane & 7) ^ srow;        // pre-swizzled source chunk

    f32x4 acc[8][4] = {};

    for (int kt = 0; kt < K / 64; ++kt) {
#pragma unroll
        for (int i = 0; i < 8; ++i) {
            const int li = wid * 8 + i;
            GLOADLDS16(A + (size_t)(bm + li * 8 + srow) * K + kt * 64 + schunk * 8,
                       &As[li * 512]);
        }
#pragma unroll
        for (int i = 0; i < 4; ++i) {
            const int li = wid * 4 + i;
            GLOADLDS16(Bt + (size_t)(bn + li * 8 + srow) * K + kt * 64 + schunk * 8,
                       &Bs[li * 512]);
        }
        __syncthreads();
#pragma unroll
        for (int ks = 0; ks < 2; ++ks) {
            bf16x8 bfr[4];
#pragma unroll
            for (int n = 0; n < 4; ++n) {
                const int row = wc * 64 + n * 16 + l15;
                const int c = (ks * 4 + lg) ^ (row & 7);
                bfr[n] = *(const bf16x8*)&Bs[row * 64 + c * 8];
            }
#pragma unroll
            for (int m = 0; m < 8; ++m) {
                const int row = wr * 128 + m * 16 + l15;
                const int c = (ks * 4 + lg) ^ (row & 7);
                const bf16x8 af = *(const bf16x8*)&As[row * 64 + c * 8];
#pragma unroll
                for (int n = 0; n < 4; ++n)
                    acc[m][n] = __builtin_amdgcn_mfma_f32_16x16x32_bf16(
                        bfr[n], af, acc[m][n], 0, 0, 0);
            }
        }
        __syncthreads();
    }
    // epilogue (C^T layout): gm = ... + l15 (fixed per lane), gn = ... + lg*4 + r
    if constexpr (MODE == 0) {
        const int which = bn >> 10;               // uniform per block (128 | 1024)
        const int hnb = (bn & 1023) + wc * 64;
        const float* bias = (which == 0) ? bias_q : (which == 1) ? bias_k : bias_v;
        if (which == 2) {
            // V transposed: vT[b][h][d][l]; lane's r-values are consecutive d
#pragma unroll
            for (int m = 0; m < 8; ++m) {
                const int gm = bm + wr * 128 + m * 16 + l15;
                const int b_ = gm >> 10, li2 = gm & 1023;
#pragma unroll
                for (int n = 0; n < 4; ++n) {
                    const int hn0 = hnb + n * 16 + lg * 4;
                    const float4 bb = *(const float4*)&bias[hn0];
                    const float vv[4] = {acc[m][n][0] + bb.x, acc[m][n][1] + bb.y,
                                         acc[m][n][2] + bb.z, acc[m][n][3] + bb.w};
#pragma unroll
                    for (int r = 0; r < 4; ++r) {
                        const int hn = hn0 + r;
                        qkv[16777216 +
                            ((size_t)(b_ * 16 + (hn >> 6)) * 64 + (hn & 63)) * 1024 +
                            li2] = f32_bf16(vv[r]);
                    }
                }
            }
        } else {
            const float qs = (which == 0) ? 0.125f * 1.44269504088896f : 1.0f;
#pragma unroll
            for (int m = 0; m < 8; ++m) {
                const int gm = bm + wr * 128 + m * 16 + l15;
                const size_t rowbase =
                    (((size_t)which * 128 + (gm >> 10) * 16) * 1024 + (gm & 1023)) * 64;
#pragma unroll
                for (int n = 0; n < 4; ++n) {
                    const int hn0 = hnb + n * 16 + lg * 4;   // 4-aligned
                    const float4 bb = *(const float4*)&bias[hn0];
                    const unsigned int w01 = bf16pk((acc[m][n][0] + bb.x) * qs,
                                                    (acc[m][n][1] + bb.y) * qs);
                    const unsigned int w23 = bf16pk((acc[m][n][2] + bb.z) * qs,
                                                    (acc[m][n][3] + bb.w) * qs);
                    uint2 t2; t2.x = w01; t2.y = w23;
                    *(uint2*)&qkv[rowbase + (size_t)(hn0 >> 6) * 65536 + (hn0 & 63)] = t2;
                }
            }
        }
    } else {
#pragma unroll
        for (int m = 0; m < 8; ++m) {
            const int gm = bm + wr * 128 + m * 16 + l15;
#pragma unroll
            for (int n = 0; n < 4; ++n) {
                const int gn0 = bn + wc * 64 + n * 16 + lg * 4;
                const float4 bb = *(const float4*)&bias_q[gn0];
                float4 o;
                o.x = acc[m][n][0] + bb.x; o.y = acc[m][n][1] + bb.y;
                o.z = acc[m][n][2] + bb.z; o.w = acc[m][n][3] + bb.w;
                *(float4*)&cout[(size_t)gm * 1024 + gn0] = o;
            }
        }
    }
}

// ---------- flash attention v5: 32 q-rows/wave, 40 KB LDS -> 3-4 blocks/CU ----------
// grid: (B*H, L/128); block 256 = 4 waves. Strips processed SEQUENTIALLY per
// tile reusing one wave-private P buffer (wave-local LDS ordering = race-free);
// V fragments preloaded to registers so V LDS reads stay single-read-dual-use.
__global__ __launch_bounds__(256, 3) void attn_kernel(
    const unsigned short* __restrict__ qkv, unsigned short* __restrict__ ctx) {
    __shared__ unsigned short Ks[2][4096];      // [key][d] XOR-swizzled, dbuf 16KB
    __shared__ unsigned short VTs[2][4096];     // [d][key] XOR-swizzled, dbuf 16KB
    __shared__ unsigned short Ps[4][1024];      // per-wave P, reused per strip, 8KB
    const int bh = blockIdx.x, qt = blockIdx.y;
    const int b = bh >> 4, h = bh & 15;
    const unsigned short* Qp  = qkv + (size_t)bh * 65536;
    const unsigned short* Kp  = qkv + 8388608  + (size_t)bh * 65536;
    const unsigned short* VTp = qkv + 16777216 + (size_t)bh * 65536;  // [64][1024]
    const int tid = threadIdx.x, wid = tid >> 6, lane = tid & 63;
    const int l15 = lane & 15, lg = lane >> 4;
    const int q0 = qt * 128 + wid * 32;         // wave owns rows q0..q0+31
    const int srow = lane >> 3;
    const int schunk = (lane & 7) ^ srow;

    // Q fragments for both strips (pre-scaled by log2e/8)
    bf16x8 qf[2][2];
#pragma unroll
    for (int s = 0; s < 2; ++s)
#pragma unroll
        for (int ks = 0; ks < 2; ++ks)
            qf[s][ks] = *(const bf16x8*)(Qp + (size_t)(q0 + s * 16 + l15) * 64 +
                                         ks * 32 + lg * 8);

    f32x4 oacc[2][4] = {};
    float lrow[2] = {0.f, 0.f};

    int koff[4][2], poff_r[2], poff_w[4];
#pragma unroll
    for (int nf = 0; nf < 4; ++nf)
#pragma unroll
        for (int ks = 0; ks < 2; ++ks) {
            const int row = nf * 16 + l15;
            koff[nf][ks] = row * 64 + (((ks * 4 + lg) ^ (row & 7)) * 8);
        }
#pragma unroll
    for (int ks = 0; ks < 2; ++ks)
        poff_r[ks] = l15 * 64 + (((ks * 4 + lg) ^ (l15 & 7)) * 8);
#pragma unroll
    for (int nf = 0; nf < 4; ++nf) {
        const int cchunk = nf * 2 + (lg >> 1);
        poff_w[nf] = l15 * 64 + ((cchunk ^ (l15 & 7)) * 8) + (lg & 1) * 4;
    }
    unsigned short* Pw = &Ps[wid][0];

#define ATTN_STAGE(KT, BB)                                                            \
    do {                                                                              \
        _Pragma("unroll")                                                             \
        for (int i = 0; i < 2; ++i) {                                                 \
            const int li = wid * 2 + i;                                               \
            GLOADLDS16(Kp + (size_t)((KT) * 64 + li * 8 + srow) * 64 + schunk * 8,    \
                       &Ks[BB][li * 512]);                                            \
            GLOADLDS16(VTp + (size_t)(li * 8 + srow) * 1024 + (KT) * 64 + schunk * 8, \
                       &VTs[BB][li * 512]);                                           \
        }                                                                             \
    } while (0)

    ATTN_STAGE(0, 0);
    for (int kt = 0; kt < 16; ++kt) {
        const int cur = kt & 1;
        if (kt < 15) {
            ATTN_STAGE(kt + 1, cur ^ 1);
            asm volatile("s_waitcnt vmcnt(4)" ::: "memory");  // tile kt landed
        } else {
            asm volatile("s_waitcnt vmcnt(0)" ::: "memory");
        }
        __builtin_amdgcn_s_barrier();

        const unsigned short* Kb = &Ks[cur][0];
        const unsigned short* Vb = &VTs[cur][0];

        // S^T = K Q^T for both strips; each kf read once, used twice
        f32x4 sacc[2][4] = {};
        __builtin_amdgcn_s_setprio(1);
#pragma unroll
        for (int ks = 0; ks < 2; ++ks)
#pragma unroll
            for (int nf = 0; nf < 4; ++nf) {
                const bf16x8 kf = *(const bf16x8*)&Kb[koff[nf][ks]];
                sacc[0][nf] = __builtin_amdgcn_mfma_f32_16x16x32_bf16(
                    kf, qf[0][ks], sacc[0][nf], 0, 0, 0);
                sacc[1][nf] = __builtin_amdgcn_mfma_f32_16x16x32_bf16(
                    kf, qf[1][ks], sacc[1][nf], 0, 0, 0);
            }
        __builtin_amdgcn_s_setprio(0);

        // V fragments -> registers (read once, used by both strips)
        bf16x8 vf[4][2];
#pragma unroll
        for (int nf = 0; nf < 4; ++nf)
#pragma unroll
            for (int ks = 0; ks < 2; ++ks)
                vf[nf][ks] = *(const bf16x8*)&Vb[koff[nf][ks]];

        // per strip: softmax -> P (wave-private LDS) -> PV
#pragma unroll
        for (int s = 0; s < 2; ++s) {
            float rsa = 0.f, rsb = 0.f;
#pragma unroll
            for (int nf = 0; nf < 4; ++nf) {
                const float p0 = fast_exp2(sacc[s][nf][0]);
                const float p1 = fast_exp2(sacc[s][nf][1]);
                const float p2 = fast_exp2(sacc[s][nf][2]);
                const float p3 = fast_exp2(sacc[s][nf][3]);
                rsa += p0 + p1; rsb += p2 + p3;
                uint2 t; t.x = bf16pk(p0, p1); t.y = bf16pk(p2, p3);
                *(uint2*)&Pw[poff_w[nf]] = t;
            }
            lrow[s] += rsa + rsb;

            __builtin_amdgcn_s_setprio(1);
#pragma unroll
            for (int ks = 0; ks < 2; ++ks) {
                const bf16x8 pf = *(const bf16x8*)&Pw[poff_r[ks]];
#pragma unroll
                for (int nf = 0; nf < 4; ++nf)
                    oacc[s][nf] = __builtin_amdgcn_mfma_f32_16x16x32_bf16(
                        vf[nf][ks], pf, oacc[s][nf], 0, 0, 0);
            }
            __builtin_amdgcn_s_setprio(0);
        }

        __builtin_amdgcn_s_barrier();
    }
#undef ATTN_STAGE

    // cross-lane l reduction + normalize + write, per strip
#pragma unroll
    for (int s = 0; s < 2; ++s) {
        float l = lrow[s];
        l += __shfl_xor(l, 16);
        l += __shfl_xor(l, 32);
        const float rl = 1.0f / l;
#pragma unroll
        for (int nf = 0; nf < 4; ++nf) {
            uint2 t;
            t.x = bf16pk(oacc[s][nf][0] * rl, oacc[s][nf][1] * rl);
            t.y = bf16pk(oacc[s][nf][2] * rl, oacc[s][nf][3] * rl);
            *(uint2*)&ctx[((size_t)(b * 1024 + q0 + s * 16 + l15)) * 1024 + h * 64 +
                          nf * 16 + lg * 4] = t;
        }
    }
}

// ---------- launch ----------
extern "C" void kernel_launch(void* const* d_in, const int* in_sizes, int n_in,
                              void* d_out, int out_size, void* d_ws, size_t ws_size,
                              hipStream_t stream) {
    (void)in_sizes; (void)n_in; (void)out_size; (void)ws_size;
    const float* x    = (const float*)d_in[0];
    const float* Wq   = (const float*)d_in[1];
    const float* bq   = (const float*)d_in[2];
    const float* Wk   = (const float*)d_in[3];
    const float* bk   = (const float*)d_in[4];
    const float* Wv   = (const float*)d_in[5];
    const float* bv   = (const float*)d_in[6];
    const float* Wo   = (const float*)d_in[7];
    const float* bo   = (const float*)d_in[8];
    const float* Wrel = (const float*)d_in[9];
    const float* brel = (const float*)d_in[10];
    float* out = (float*)d_out;

    char* ws = (char*)d_ws;
    unsigned short* xb    = (unsigned short*)ws;                           // 16 MB
    unsigned short* wqkvT = (unsigned short*)(ws + 16777216);              // 6 MB
    unsigned short* woT   = (unsigned short*)(ws + 16777216 + 6291456);    // 2 MB
    unsigned short* qkv   = (unsigned short*)(ws + 16777216 + 6291456 + 2097152); // 48 MB
    unsigned short* ctx   = xb;  // xb dead after QKV GEMM -> reuse for ctx

    prep_kernel<<<12289, 256, 0, stream>>>(x, Wq, Wk, Wv, Wo, Wrel, brel,
                                           xb, wqkvT, woT, out);
    gemm_bt_kernel<0><<<dim3(32, 24), 256, 0, stream>>>(
        xb, wqkvT, bq, bk, bv, qkv, nullptr);
    attn_kernel<<<dim3(128, 8), 256, 0, stream>>>(qkv, ctx);
    gemm_bt_kernel<1><<<dim3(32, 8), 256, 0, stream>>>(
        ctx, woT, bo, nullptr, nullptr, nullptr, out);
}

// Round 14
// 159.334 us; speedup vs baseline: 1.1348x; 1.0043x over previous
//
#include <hip/hip_runtime.h>
#include <math.h>

// ---------- types ----------
using f32x4  = __attribute__((ext_vector_type(4))) float;
using bf16x8 = __attribute__((ext_vector_type(8))) short;   // 8 bf16 in 4 VGPRs
using us8    = __attribute__((ext_vector_type(8))) unsigned short;
using us4    = __attribute__((ext_vector_type(4))) unsigned short;

static __device__ __forceinline__ unsigned short f32_bf16(float f) {
    unsigned int u = __float_as_uint(f);
    u += 0x7fffu + ((u >> 16) & 1u);       // round-to-nearest-even
    return (unsigned short)(u >> 16);
}

static __device__ __forceinline__ float fast_exp2(float x) {
    return __builtin_amdgcn_exp2f(x);      // v_exp_f32 (2^x)
}

// pack 2 f32 -> 2 bf16 in one u32 (RNE), single instruction
static __device__ __forceinline__ unsigned int bf16pk(float lo, float hi) {
    unsigned int r;
    asm("v_cvt_pk_bf16_f32 %0, %1, %2" : "=v"(r) : "v"(lo), "v"(hi));
    return r;
}

// global -> LDS direct copy, 16B per lane. LDS dest is wave-uniform base +
// lane*16 (linear); swizzling is done on the per-lane GLOBAL source address.
#define GLOADLDS16(src, dst)                                                          \
    __builtin_amdgcn_global_load_lds(                                                 \
        (const __attribute__((address_space(1))) void*)(src),                         \
        (__attribute__((address_space(3))) void*)(dst), 16, 0, 0)

// ---------- fused prep: x->bf16 | W->W^T bf16 | relation scores ----------
__global__ __launch_bounds__(256) void prep_kernel(
    const float* __restrict__ x, const float* __restrict__ Wq,
    const float* __restrict__ Wk, const float* __restrict__ Wv,
    const float* __restrict__ Wo, const float* __restrict__ Wrel,
    const float* __restrict__ brel, unsigned short* __restrict__ xb,
    unsigned short* __restrict__ wqkvT, unsigned short* __restrict__ woT,
    float* __restrict__ out) {
    const int bid = blockIdx.x;
    if (bid < 8192) {                       // conv_x: 2M float4s
        const int i = bid * 256 + threadIdx.x;
        const float4 v = ((const float4*)x)[i];
        us4 o;
        o.x = f32_bf16(v.x); o.y = f32_bf16(v.y);
        o.z = f32_bf16(v.z); o.w = f32_bf16(v.w);
        ((us4*)xb)[i] = o;
        return;
    }
    if (bid < 12288) {                      // conv_wT: transpose 4 weight mats
        __shared__ float t[32][33];
        const int z = bid - 8192;
        const int zz = z >> 10;             // 0..3
        const float* W = (zz == 0) ? Wq : (zz == 1) ? Wk : (zz == 2) ? Wv : Wo;
        unsigned short* dst = (zz < 3) ? (wqkvT + (size_t)zz * 1024 * 1024) : woT;
        const int bx = (z & 31) * 32, by = ((z >> 5) & 31) * 32;
        const int tx = threadIdx.x & 31, ty = threadIdx.x >> 5;
#pragma unroll
        for (int i = ty; i < 32; i += 8)
            t[i][tx] = W[(size_t)(by + i) * 1024 + bx + tx];
        __syncthreads();
#pragma unroll
        for (int i = ty; i < 32; i += 8)
            dst[(size_t)(bx + i) * 1024 + by + tx] = f32_bf16(t[tx][i]);
        return;
    }
    // relation scores: softmax rows sum to 1 -> head_patterns == 1/L exactly
    const int t = threadIdx.x;
    if (t < 64) {
        const int r = t & 7;
        float s = 0.f;
#pragma unroll
        for (int hh = 0; hh < 16; ++hh) s += Wrel[hh * 8 + r];
        out[8 * 1024 * 1024 + t] = s * (1.0f / 1024.0f) + brel[r];
    }
}

// ---------- GEMM (round-9 best, FROZEN): 256x128 tile, 256 thr, acc[8][4] ----------
// C[M,N] = A[M,K] * Bt[N,K]^T, K=1024. Per-wave 128x64 -> 6 B LDS read/MFMA.
// Single-buffer 48 KB LDS, 2 blocks/CU. Plain 2-sync loop: 5 schedule variants
// (R5/R6/R7/R11-ring/R12) all regressed vs this -- compiler+co-residency wins.
// Operands SWAPPED in mfma (C^T): lane holds 4 consecutive N.
template<int MODE>
__global__ __launch_bounds__(256, 2) void gemm_bt_kernel(
    const unsigned short* __restrict__ A, const unsigned short* __restrict__ Bt,
    const float* __restrict__ bias_q, const float* __restrict__ bias_k,
    const float* __restrict__ bias_v,
    unsigned short* __restrict__ qkv, float* __restrict__ cout) {
    constexpr int K = 1024;
    __shared__ unsigned short As[256 * 64];   // 32 KB
    __shared__ unsigned short Bs[128 * 64];   // 16 KB
    const int tid = threadIdx.x;
    const int wid = tid >> 6, lane = tid & 63;
    const int bm = blockIdx.x * 256, bn = blockIdx.y * 128;
    const int wr = wid >> 1, wc = wid & 1;       // 2x2 waves; wave tile 128x64
    const int l15 = lane & 15, lg = lane >> 4;
    const int srow = lane >> 3;                  // row-within-8 for staging
    const int schunk = (lane & 7) ^ srow;        // pre-swizzled source chunk

    f32x4 acc[8][4] = {};

    for (int kt = 0; kt < K / 64; ++kt) {
#pragma unroll
        for (int i = 0; i < 8; ++i) {
            const int li = wid * 8 + i;
            GLOADLDS16(A + (size_t)(bm + li * 8 + srow) * K + kt * 64 + schunk * 8,
                       &As[li * 512]);
        }
#pragma unroll
        for (int i = 0; i < 4; ++i) {
            const int li = wid * 4 + i;
            GLOADLDS16(Bt + (size_t)(bn + li * 8 + srow) * K + kt * 64 + schunk * 8,
                       &Bs[li * 512]);
        }
        __syncthreads();
#pragma unroll
        for (int ks = 0; ks < 2; ++ks) {
            bf16x8 bfr[4];
#pragma unroll
            for (int n = 0; n < 4; ++n) {
                const int row = wc * 64 + n * 16 + l15;
                const int c = (ks * 4 + lg) ^ (row & 7);
                bfr[n] = *(const bf16x8*)&Bs[row * 64 + c * 8];
            }
#pragma unroll
            for (int m = 0; m < 8; ++m) {
                const int row = wr * 128 + m * 16 + l15;
                const int c = (ks * 4 + lg) ^ (row & 7);
                const bf16x8 af = *(const bf16x8*)&As[row * 64 + c * 8];
#pragma unroll
                for (int n = 0; n < 4; ++n)
                    acc[m][n] = __builtin_amdgcn_mfma_f32_16x16x32_bf16(
                        bfr[n], af, acc[m][n], 0, 0, 0);
            }
        }
        __syncthreads();
    }
    // epilogue (C^T layout): gm = ... + l15 (fixed per lane), gn = ... + lg*4 + r
    if constexpr (MODE == 0) {
        const int which = bn >> 10;               // uniform per block (128 | 1024)
        const int hnb = (bn & 1023) + wc * 64;
        const float* bias = (which == 0) ? bias_q : (which == 1) ? bias_k : bias_v;
        if (which == 2) {
            // V transposed: vT[b][h][d][l]; lane's r-values are consecutive d
#pragma unroll
            for (int m = 0; m < 8; ++m) {
                const int gm = bm + wr * 128 + m * 16 + l15;
                const int b_ = gm >> 10, li2 = gm & 1023;
#pragma unroll
                for (int n = 0; n < 4; ++n) {
                    const int hn0 = hnb + n * 16 + lg * 4;
                    const float4 bb = *(const float4*)&bias[hn0];
                    const float vv[4] = {acc[m][n][0] + bb.x, acc[m][n][1] + bb.y,
                                         acc[m][n][2] + bb.z, acc[m][n][3] + bb.w};
#pragma unroll
                    for (int r = 0; r < 4; ++r) {
                        const int hn = hn0 + r;
                        qkv[16777216 +
                            ((size_t)(b_ * 16 + (hn >> 6)) * 64 + (hn & 63)) * 1024 +
                            li2] = f32_bf16(vv[r]);
                    }
                }
            }
        } else {
            const float qs = (which == 0) ? 0.125f * 1.44269504088896f : 1.0f;
#pragma unroll
            for (int m = 0; m < 8; ++m) {
                const int gm = bm + wr * 128 + m * 16 + l15;
                const size_t rowbase =
                    (((size_t)which * 128 + (gm >> 10) * 16) * 1024 + (gm & 1023)) * 64;
#pragma unroll
                for (int n = 0; n < 4; ++n) {
                    const int hn0 = hnb + n * 16 + lg * 4;   // 4-aligned
                    const float4 bb = *(const float4*)&bias[hn0];
                    const unsigned int w01 = bf16pk((acc[m][n][0] + bb.x) * qs,
                                                    (acc[m][n][1] + bb.y) * qs);
                    const unsigned int w23 = bf16pk((acc[m][n][2] + bb.z) * qs,
                                                    (acc[m][n][3] + bb.w) * qs);
                    uint2 t2; t2.x = w01; t2.y = w23;
                    *(uint2*)&qkv[rowbase + (size_t)(hn0 >> 6) * 65536 + (hn0 & 63)] = t2;
                }
            }
        }
    } else {
#pragma unroll
        for (int m = 0; m < 8; ++m) {
            const int gm = bm + wr * 128 + m * 16 + l15;
#pragma unroll
            for (int n = 0; n < 4; ++n) {
                const int gn0 = bn + wc * 64 + n * 16 + lg * 4;
                const float4 bb = *(const float4*)&bias_q[gn0];
                float4 o;
                o.x = acc[m][n][0] + bb.x; o.y = acc[m][n][1] + bb.y;
                o.z = acc[m][n][2] + bb.z; o.w = acc[m][n][3] + bb.w;
                *(float4*)&cout[(size_t)gm * 1024 + gn0] = o;
            }
        }
    }
}

// ---------- flash attention v6: v5 + dual per-strip P buffer (no WAR) ----------
// grid: (B*H, L/128); block 256 = 4 waves, 32 q-rows/wave as two 16-row strips.
// Strips sequential but write DIFFERENT P buffers -> strip1's softmax VALU can
// overlap strip0's PV MFMAs (no LDS WAR between them). V frags preloaded to
// registers (read once, used by both strips). 48 KB LDS -> 3 blocks/CU.
__global__ __launch_bounds__(256, 3) void attn_kernel(
    const unsigned short* __restrict__ qkv, unsigned short* __restrict__ ctx) {
    __shared__ unsigned short Ks[2][4096];      // [key][d] XOR-swizzled, dbuf 16KB
    __shared__ unsigned short VTs[2][4096];     // [d][key] XOR-swizzled, dbuf 16KB
    __shared__ unsigned short Ps[4][2][1024];   // per-wave PER-STRIP P, 16KB
    const int bh = blockIdx.x, qt = blockIdx.y;
    const int b = bh >> 4, h = bh & 15;
    const unsigned short* Qp  = qkv + (size_t)bh * 65536;
    const unsigned short* Kp  = qkv + 8388608  + (size_t)bh * 65536;
    const unsigned short* VTp = qkv + 16777216 + (size_t)bh * 65536;  // [64][1024]
    const int tid = threadIdx.x, wid = tid >> 6, lane = tid & 63;
    const int l15 = lane & 15, lg = lane >> 4;
    const int q0 = qt * 128 + wid * 32;         // wave owns rows q0..q0+31
    const int srow = lane >> 3;
    const int schunk = (lane & 7) ^ srow;

    // Q fragments for both strips (pre-scaled by log2e/8)
    bf16x8 qf[2][2];
#pragma unroll
    for (int s = 0; s < 2; ++s)
#pragma unroll
        for (int ks = 0; ks < 2; ++ks)
            qf[s][ks] = *(const bf16x8*)(Qp + (size_t)(q0 + s * 16 + l15) * 64 +
                                         ks * 32 + lg * 8);

    f32x4 oacc[2][4] = {};
    float lrow[2] = {0.f, 0.f};

    int koff[4][2], poff_r[2], poff_w[4];
#pragma unroll
    for (int nf = 0; nf < 4; ++nf)
#pragma unroll
        for (int ks = 0; ks < 2; ++ks) {
            const int row = nf * 16 + l15;
            koff[nf][ks] = row * 64 + (((ks * 4 + lg) ^ (row & 7)) * 8);
        }
#pragma unroll
    for (int ks = 0; ks < 2; ++ks)
        poff_r[ks] = l15 * 64 + (((ks * 4 + lg) ^ (l15 & 7)) * 8);
#pragma unroll
    for (int nf = 0; nf < 4; ++nf) {
        const int cchunk = nf * 2 + (lg >> 1);
        poff_w[nf] = l15 * 64 + ((cchunk ^ (l15 & 7)) * 8) + (lg & 1) * 4;
    }

#define ATTN_STAGE(KT, BB)                                                            \
    do {                                                                              \
        _Pragma("unroll")                                                             \
        for (int i = 0; i < 2; ++i) {                                                 \
            const int li = wid * 2 + i;                                               \
            GLOADLDS16(Kp + (size_t)((KT) * 64 + li * 8 + srow) * 64 + schunk * 8,    \
                       &Ks[BB][li * 512]);                                            \
            GLOADLDS16(VTp + (size_t)(li * 8 + srow) * 1024 + (KT) * 64 + schunk * 8, \
                       &VTs[BB][li * 512]);                                           \
        }                                                                             \
    } while (0)

    ATTN_STAGE(0, 0);
    for (int kt = 0; kt < 16; ++kt) {
        const int cur = kt & 1;
        if (kt < 15) {
            ATTN_STAGE(kt + 1, cur ^ 1);
            asm volatile("s_waitcnt vmcnt(4)" ::: "memory");  // tile kt landed
        } else {
            asm volatile("s_waitcnt vmcnt(0)" ::: "memory");
        }
        __builtin_amdgcn_s_barrier();

        const unsigned short* Kb = &Ks[cur][0];
        const unsigned short* Vb = &VTs[cur][0];

        // S^T = K Q^T for both strips; each kf read once, used twice
        f32x4 sacc[2][4] = {};
        __builtin_amdgcn_s_setprio(1);
#pragma unroll
        for (int ks = 0; ks < 2; ++ks)
#pragma unroll
            for (int nf = 0; nf < 4; ++nf) {
                const bf16x8 kf = *(const bf16x8*)&Kb[koff[nf][ks]];
                sacc[0][nf] = __builtin_amdgcn_mfma_f32_16x16x32_bf16(
                    kf, qf[0][ks], sacc[0][nf], 0, 0, 0);
                sacc[1][nf] = __builtin_amdgcn_mfma_f32_16x16x32_bf16(
                    kf, qf[1][ks], sacc[1][nf], 0, 0, 0);
            }
        __builtin_amdgcn_s_setprio(0);

        // V fragments -> registers (read once, used by both strips)
        bf16x8 vf[4][2];
#pragma unroll
        for (int nf = 0; nf < 4; ++nf)
#pragma unroll
            for (int ks = 0; ks < 2; ++ks)
                vf[nf][ks] = *(const bf16x8*)&Vb[koff[nf][ks]];

        // per strip: softmax -> P (strip-private LDS buffer) -> PV.
        // Distinct buffers => no WAR between strip0's PV reads and strip1's
        // P writes; compiler can overlap strip1 VALU with strip0 MFMA.
#pragma unroll
        for (int s = 0; s < 2; ++s) {
            unsigned short* Pw = &Ps[wid][s][0];
            float rsa = 0.f, rsb = 0.f;
#pragma unroll
            for (int nf = 0; nf < 4; ++nf) {
                const float p0 = fast_exp2(sacc[s][nf][0]);
                const float p1 = fast_exp2(sacc[s][nf][1]);
                const float p2 = fast_exp2(sacc[s][nf][2]);
                const float p3 = fast_exp2(sacc[s][nf][3]);
                rsa += p0 + p1; rsb += p2 + p3;
                uint2 t; t.x = bf16pk(p0, p1); t.y = bf16pk(p2, p3);
                *(uint2*)&Pw[poff_w[nf]] = t;
            }
            lrow[s] += rsa + rsb;

            __builtin_amdgcn_s_setprio(1);
#pragma unroll
            for (int ks = 0; ks < 2; ++ks) {
                const bf16x8 pf = *(const bf16x8*)&Pw[poff_r[ks]];
#pragma unroll
                for (int nf = 0; nf < 4; ++nf)
                    oacc[s][nf] = __builtin_amdgcn_mfma_f32_16x16x32_bf16(
                        vf[nf][ks], pf, oacc[s][nf], 0, 0, 0);
            }
            __builtin_amdgcn_s_setprio(0);
        }

        __builtin_amdgcn_s_barrier();
    }
#undef ATTN_STAGE

    // cross-lane l reduction + normalize + write, per strip
#pragma unroll
    for (int s = 0; s < 2; ++s) {
        float l = lrow[s];
        l += __shfl_xor(l, 16);
        l += __shfl_xor(l, 32);
        const float rl = 1.0f / l;
#pragma unroll
        for (int nf = 0; nf < 4; ++nf) {
            uint2 t;
            t.x = bf16pk(oacc[s][nf][0] * rl, oacc[s][nf][1] * rl);
            t.y = bf16pk(oacc[s][nf][2] * rl, oacc[s][nf][3] * rl);
            *(uint2*)&ctx[((size_t)(b * 1024 + q0 + s * 16 + l15)) * 1024 + h * 64 +
                          nf * 16 + lg * 4] = t;
        }
    }
}

// ---------- launch ----------
extern "C" void kernel_launch(void* const* d_in, const int* in_sizes, int n_in,
                              void* d_out, int out_size, void* d_ws, size_t ws_size,
                              hipStream_t stream) {
    (void)in_sizes; (void)n_in; (void)out_size; (void)ws_size;
    const float* x    = (const float*)d_in[0];
    const float* Wq   = (const float*)d_in[1];
    const float* bq   = (const float*)d_in[2];
    const float* Wk   = (const float*)d_in[3];
    const float* bk   = (const float*)d_in[4];
    const float* Wv   = (const float*)d_in[5];
    const float* bv   = (const float*)d_in[6];
    const float* Wo   = (const float*)d_in[7];
    const float* bo   = (const float*)d_in[8];
    const float* Wrel = (const float*)d_in[9];
    const float* brel = (const float*)d_in[10];
    float* out = (float*)d_out;

    char* ws = (char*)d_ws;
    unsigned short* xb    = (unsigned short*)ws;                           // 16 MB
    unsigned short* wqkvT = (unsigned short*)(ws + 16777216);              // 6 MB
    unsigned short* woT   = (unsigned short*)(ws + 16777216 + 6291456);    // 2 MB
    unsigned short* qkv   = (unsigned short*)(ws + 16777216 + 6291456 + 2097152); // 48 MB
    unsigned short* ctx   = xb;  // xb dead after QKV GEMM -> reuse for ctx

    prep_kernel<<<12289, 256, 0, stream>>>(x, Wq, Wk, Wv, Wo, Wrel, brel,
                                           xb, wqkvT, woT, out);
    gemm_bt_kernel<0><<<dim3(32, 24), 256, 0, stream>>>(
        xb, wqkvT, bq, bk, bv, qkv, nullptr);
    attn_kernel<<<dim3(128, 8), 256, 0, stream>>>(qkv, ctx);
    gemm_bt_kernel<1><<<dim3(32, 8), 256, 0, stream>>>(
        ctx, woT, bo, nullptr, nullptr, nullptr, out);
}